// Round 1
// baseline (383.478 us; speedup 1.0000x reference)
//
#include <hip/hip_runtime.h>
#include <hip/hip_bf16.h>
#include <cstdint>

#define N_NODES 4096
#define STRIDE  512      // max neighbors per row we store (E[count]=205, max~260)

// ---------------------------------------------------------------------------
// 1. Neighbor-list compaction: one wave (64 lanes) per row, ballot+popcount.
//    Deterministic (sorted) order.
// ---------------------------------------------------------------------------
__global__ __launch_bounds__(64) void build_nbr_kernel(
    const float* __restrict__ adj, int* __restrict__ nbr, int* __restrict__ cnt) {
    const int i    = blockIdx.x;
    const int lane = threadIdx.x;
    const float* row = adj + (size_t)i * N_NODES;
    int base = 0;
    for (int jb = 0; jb < N_NODES; jb += 64) {
        float v = row[jb + lane];
        unsigned long long mask = __ballot(v != 0.0f);
        int prefix = __popcll(mask & ((1ull << lane) - 1ull));
        int pos = base + prefix;
        if (v != 0.0f && pos < STRIDE)
            nbr[(size_t)i * STRIDE + pos] = jb + lane;
        base += __popcll(mask);
    }
    if (lane == 0) cnt[i] = (base < STRIDE) ? base : STRIDE;
}

// ---------------------------------------------------------------------------
// 2. Tiled fp32 GEMM: C[M,N] = A[M,K] @ B[K,N].  BM=BN=64, BK=16, 256 thr,
//    4x4 micro-tile per thread.  Dims assumed divisible.
// ---------------------------------------------------------------------------
template<int BM, int BN, int BK>
__global__ __launch_bounds__(256) void sgemm_kernel(
    const float* __restrict__ A, const float* __restrict__ B,
    float* __restrict__ C, int M, int N, int K) {
    __shared__ float As[BM][BK + 1];
    __shared__ float Bs[BK][BN];
    const int tid  = threadIdx.x;
    const int tx   = tid % (BN / 4);   // 16
    const int ty   = tid / (BN / 4);   // 16
    const int row0 = blockIdx.y * BM;
    const int col0 = blockIdx.x * BN;
    float acc[4][4] = {};
    for (int k0 = 0; k0 < K; k0 += BK) {
        for (int idx = tid; idx < BM * BK; idx += 256) {
            int r = idx / BK, c = idx % BK;
            As[r][c] = A[(size_t)(row0 + r) * K + k0 + c];
        }
        for (int idx = tid; idx < BK * BN; idx += 256) {
            int r = idx / BN, c = idx % BN;
            Bs[r][c] = B[(size_t)(k0 + r) * N + col0 + c];
        }
        __syncthreads();
#pragma unroll
        for (int kk = 0; kk < BK; kk++) {
            float a[4], b[4];
#pragma unroll
            for (int t = 0; t < 4; t++) a[t] = As[ty * 4 + t][kk];
#pragma unroll
            for (int t = 0; t < 4; t++) b[t] = Bs[kk][tx * 4 + t];
#pragma unroll
            for (int u = 0; u < 4; u++)
#pragma unroll
                for (int v = 0; v < 4; v++) acc[u][v] += a[u] * b[v];
        }
        __syncthreads();
    }
#pragma unroll
    for (int u = 0; u < 4; u++)
#pragma unroll
        for (int v = 0; v < 4; v++)
            C[(size_t)(row0 + ty * 4 + u) * N + col0 + tx * 4 + v] = acc[u][v];
}

// ---------------------------------------------------------------------------
// 3. Per-node attention scores: a_src[n,h] = <h[n,h,:], att_src[h,:]>, same dst.
//    One wave per node.
// ---------------------------------------------------------------------------
__global__ __launch_bounds__(64) void scores_kernel(
    const float* __restrict__ h, const float* __restrict__ att_s,
    const float* __restrict__ att_d, float* __restrict__ as_,
    float* __restrict__ ad_, int H, int C) {
    const int n = blockIdx.x, lane = threadIdx.x;
    for (int hh = 0; hh < H; hh++) {
        float s = 0.f, d = 0.f;
        for (int c = lane; c < C; c += 64) {
            float v = h[((size_t)n * H + hh) * C + c];
            s += v * att_s[hh * C + c];
            d += v * att_d[hh * C + c];
        }
#pragma unroll
        for (int off = 32; off; off >>= 1) {
            s += __shfl_xor(s, off);
            d += __shfl_xor(d, off);
        }
        if (lane == 0) { as_[n * H + hh] = s; ad_[n * H + hh] = d; }
    }
}

// ---------------------------------------------------------------------------
// 4. Layer-1 sparse attention aggregate. One block (128 thr) per row i.
//    tid = head(8) x lane16(16); each lane owns 4 channels (float4).
//    Epilogue: + b1, leaky_relu(0.01)  -> out1 (ready as GEMM2 input).
// ---------------------------------------------------------------------------
__global__ __launch_bounds__(128) void attn1_kernel(
    const float* __restrict__ h1, const float* __restrict__ asrc,
    const float* __restrict__ adst, const int* __restrict__ nbr,
    const int* __restrict__ cnt, const float* __restrict__ b1,
    float* __restrict__ out1) {
    const int i   = blockIdx.x;
    const int tid = threadIdx.x;
    const int hs  = tid >> 4;     // head 0..7
    const int l16 = tid & 15;     // lane within head-group
    __shared__ int   s_nbr[STRIDE];
    __shared__ float s_w[8][STRIDE];    // 16 KB
    const int n = cnt[i];
    for (int j = tid; j < n; j += 128) s_nbr[j] = nbr[(size_t)i * STRIDE + j];
    __syncthreads();

    const float ad = adst[i * 8 + hs];
    // pass 1: raw scores + max  (reduce over 16-lane group: xor offsets 8..1)
    float m = -1e30f;
    for (int j = l16; j < n; j += 16) {
        float s = asrc[s_nbr[j] * 8 + hs] + ad;
        s = (s > 0.f) ? s : 0.2f * s;
        s_w[hs][j] = s;
        m = fmaxf(m, s);
    }
#pragma unroll
    for (int off = 8; off; off >>= 1) m = fmaxf(m, __shfl_xor(m, off));
    // pass 2: exp + sum
    float l = 0.f;
    for (int j = l16; j < n; j += 16) {
        float e = __expf(s_w[hs][j] - m);
        s_w[hs][j] = e;
        l += e;
    }
#pragma unroll
    for (int off = 8; off; off >>= 1) l += __shfl_xor(l, off);
    const float inv = 1.0f / l;
    __syncthreads();   // make all s_w visible to all lanes of the head group

    // pass 3: weighted gather-accumulate (coalesced: block reads 2 KB/row slice)
    float4 acc = make_float4(0.f, 0.f, 0.f, 0.f);
    const int c0 = hs * 64 + l16 * 4;
    for (int j = 0; j < n; j++) {
        const float  w = s_w[hs][j];
        const float4 v = *(const float4*)(h1 + (size_t)s_nbr[j] * 512 + c0);
        acc.x += w * v.x; acc.y += w * v.y; acc.z += w * v.z; acc.w += w * v.w;
    }
    float4 bb = *(const float4*)(b1 + c0);
    float o0 = acc.x * inv + bb.x, o1 = acc.y * inv + bb.y;
    float o2 = acc.z * inv + bb.z, o3 = acc.w * inv + bb.w;
    o0 = (o0 > 0.f) ? o0 : 0.01f * o0;
    o1 = (o1 > 0.f) ? o1 : 0.01f * o1;
    o2 = (o2 > 0.f) ? o2 : 0.01f * o2;
    o3 = (o3 > 0.f) ? o3 : 0.01f * o3;
    *(float4*)(out1 + (size_t)i * 512 + c0) = make_float4(o0, o1, o2, o3);
}

// ---------------------------------------------------------------------------
// 5. Layer-2 sparse attention aggregate (1 head, 128 channels).
//    One block (128 thr) per row; epilogue + b2, leaky(0.01) -> d_out.
// ---------------------------------------------------------------------------
__global__ __launch_bounds__(128) void attn2_kernel(
    const float* __restrict__ h2, const float* __restrict__ asrc,
    const float* __restrict__ adst, const int* __restrict__ nbr,
    const int* __restrict__ cnt, const float* __restrict__ b2,
    float* __restrict__ out) {
    const int i   = blockIdx.x;
    const int tid = threadIdx.x;
    __shared__ int   s_nbr[STRIDE];
    __shared__ float s_w[STRIDE];
    __shared__ float red[2], red2[2];
    const int n = cnt[i];
    for (int j = tid; j < n; j += 128) s_nbr[j] = nbr[(size_t)i * STRIDE + j];
    __syncthreads();

    const float ad = adst[i];
    float mloc = -1e30f;
    for (int j = tid; j < n; j += 128) {
        float s = asrc[s_nbr[j]] + ad;
        s = (s > 0.f) ? s : 0.2f * s;
        s_w[j] = s;
        mloc = fmaxf(mloc, s);
    }
#pragma unroll
    for (int off = 32; off; off >>= 1) mloc = fmaxf(mloc, __shfl_xor(mloc, off));
    if ((tid & 63) == 0) red[tid >> 6] = mloc;
    __syncthreads();
    const float m = fmaxf(red[0], red[1]);
    float lloc = 0.f;
    for (int j = tid; j < n; j += 128) {
        float e = __expf(s_w[j] - m);
        s_w[j] = e;
        lloc += e;
    }
#pragma unroll
    for (int off = 32; off; off >>= 1) lloc += __shfl_xor(lloc, off);
    if ((tid & 63) == 0) red2[tid >> 6] = lloc;
    __syncthreads();
    const float inv = 1.0f / (red2[0] + red2[1]);

    float acc = 0.f;
    for (int j = 0; j < n; j++)
        acc += s_w[j] * h2[(size_t)s_nbr[j] * 128 + tid];
    float o = acc * inv + b2[tid];
    out[(size_t)i * 128 + tid] = (o > 0.f) ? o : 0.01f * o;
}

// ---------------------------------------------------------------------------
extern "C" void kernel_launch(void* const* d_in, const int* in_sizes, int n_in,
                              void* d_out, int out_size, void* d_ws, size_t ws_size,
                              hipStream_t stream) {
    const float* x        = (const float*)d_in[0];   // [4096,256]
    const float* adj      = (const float*)d_in[1];   // [4096,4096]
    const float* w1       = (const float*)d_in[2];   // [256,512]
    const float* att_src1 = (const float*)d_in[3];   // [8,64]
    const float* att_dst1 = (const float*)d_in[4];
    const float* b1       = (const float*)d_in[5];   // [512]
    const float* w2       = (const float*)d_in[6];   // [512,128]
    const float* att_src2 = (const float*)d_in[7];   // [1,128]
    const float* att_dst2 = (const float*)d_in[8];
    const float* b2       = (const float*)d_in[9];   // [128]
    float* out = (float*)d_out;                      // [4096,128]

    // workspace layout (floats)
    float* ws   = (float*)d_ws;
    float* h1   = ws;                         // 4096*512
    float* out1 = h1 + 4096 * 512;            // 4096*512
    float* h2   = out1 + 4096 * 512;          // 4096*128
    float* as1  = h2 + 4096 * 128;            // 4096*8
    float* ad1  = as1 + 4096 * 8;             // 4096*8
    float* as2  = ad1 + 4096 * 8;             // 4096
    float* ad2  = as2 + 4096;                 // 4096
    int*   cnt  = (int*)(ad2 + 4096);         // 4096
    int*   nbr  = (int*)(cnt + 4096);         // 4096*STRIDE

    build_nbr_kernel<<<N_NODES, 64, 0, stream>>>(adj, nbr, cnt);

    // layer 1
    sgemm_kernel<64, 64, 16><<<dim3(512 / 64, 4096 / 64), 256, 0, stream>>>(
        x, w1, h1, 4096, 512, 256);
    scores_kernel<<<N_NODES, 64, 0, stream>>>(h1, att_src1, att_dst1, as1, ad1, 8, 64);
    attn1_kernel<<<N_NODES, 128, 0, stream>>>(h1, as1, ad1, nbr, cnt, b1, out1);

    // layer 2
    sgemm_kernel<64, 64, 16><<<dim3(128 / 64, 4096 / 64), 256, 0, stream>>>(
        out1, w2, h2, 4096, 128, 512);
    scores_kernel<<<N_NODES, 64, 0, stream>>>(h2, att_src2, att_dst2, as2, ad2, 1, 128);
    attn2_kernel<<<N_NODES, 128, 0, stream>>>(h2, as2, ad2, nbr, cnt, b2, out);
}

// Round 2
// 330.574 us; speedup vs baseline: 1.1600x; 1.1600x over previous
//
#include <hip/hip_runtime.h>
#include <hip/hip_bf16.h>
#include <cstdint>

#define N_NODES 4096
#define STRIDE  384      // max degree ~270 (Binom(4096,0.05), 8-sigma margin)
#define SWPAD   (STRIDE + 8)   // s_w row stride: 392%32=8 -> heads land on distinct banks

// ---------------------------------------------------------------------------
// 1. Neighbor-list compaction: one wave per row, float4 loads + 4 ballots.
//    Order is e-major within each 256-col chunk (NOT sorted; order only
//    perturbs fp32 summation rounding, which is within threshold).
// ---------------------------------------------------------------------------
__global__ __launch_bounds__(64) void build_nbr_kernel(
    const float* __restrict__ adj, int* __restrict__ nbr, int* __restrict__ cnt) {
    const int i    = blockIdx.x;
    const int lane = threadIdx.x;
    const float4* row = (const float4*)(adj + (size_t)i * N_NODES);
    int base = 0;
    for (int jb = 0; jb < N_NODES / 4; jb += 64) {   // 16 iterations
        float4 v = row[jb + lane];
        float e4[4] = {v.x, v.y, v.z, v.w};
#pragma unroll
        for (int e = 0; e < 4; e++) {
            unsigned long long mask = __ballot(e4[e] != 0.0f);
            int prefix = __popcll(mask & ((1ull << lane) - 1ull));
            int pos = base + prefix;
            if (e4[e] != 0.0f && pos < STRIDE)
                nbr[(size_t)i * STRIDE + pos] = (jb + lane) * 4 + e;
            base += __popcll(mask);
        }
    }
    if (lane == 0) cnt[i] = (base < STRIDE) ? base : STRIDE;
}

// ---------------------------------------------------------------------------
// 2. Tiled fp32 GEMM: C[M,N] = A[M,K] @ B[K,N]. 256 threads,
//    (BM/TM)x(BN/TN)=16x16 thread grid, float4 global loads, A staged K-major.
// ---------------------------------------------------------------------------
template<int BM, int BN, int BK, int TM, int TN>
__global__ __launch_bounds__(256) void sgemm_kernel(
    const float* __restrict__ A, const float* __restrict__ B,
    float* __restrict__ C, int M, int N, int K) {
    static_assert((BM / TM) * (BN / TN) == 256, "256 threads");
    __shared__ float As[BK][BM + 4];   // K-major so a[TM] reads are contiguous
    __shared__ float Bs[BK][BN + 4];
    const int tid  = threadIdx.x;
    const int tx   = tid % (BN / TN);
    const int ty   = tid / (BN / TN);
    const int row0 = blockIdx.y * BM;
    const int col0 = blockIdx.x * BN;
    float acc[TM][TN] = {};
    for (int k0 = 0; k0 < K; k0 += BK) {
        // A tile: load float4 along K, transpose into As[k][m]
        for (int i = tid; i < BM * BK / 4; i += 256) {
            int r  = i / (BK / 4);
            int kq = i % (BK / 4);
            float4 v = *(const float4*)(A + (size_t)(row0 + r) * K + k0 + kq * 4);
            As[kq * 4 + 0][r] = v.x;
            As[kq * 4 + 1][r] = v.y;
            As[kq * 4 + 2][r] = v.z;
            As[kq * 4 + 3][r] = v.w;
        }
        // B tile: natural layout, float4
        for (int i = tid; i < BK * BN / 4; i += 256) {
            int r  = i / (BN / 4);
            int cq = i % (BN / 4);
            *(float4*)&Bs[r][cq * 4] =
                *(const float4*)(B + (size_t)(k0 + r) * N + col0 + cq * 4);
        }
        __syncthreads();
#pragma unroll
        for (int kk = 0; kk < BK; kk++) {
            float a[TM], b[TN];
#pragma unroll
            for (int t = 0; t < TM; t++) a[t] = As[kk][ty * TM + t];
#pragma unroll
            for (int u = 0; u < TN; u++) b[u] = Bs[kk][tx * TN + u];
#pragma unroll
            for (int t = 0; t < TM; t++)
#pragma unroll
                for (int u = 0; u < TN; u++) acc[t][u] += a[t] * b[u];
        }
        __syncthreads();
    }
#pragma unroll
    for (int t = 0; t < TM; t++)
#pragma unroll
        for (int u4 = 0; u4 < TN / 4; u4++) {
            float4 v = make_float4(acc[t][u4 * 4 + 0], acc[t][u4 * 4 + 1],
                                   acc[t][u4 * 4 + 2], acc[t][u4 * 4 + 3]);
            *(float4*)(C + (size_t)(row0 + ty * TM + t) * N + col0 + tx * TN + u4 * 4) = v;
        }
}

// ---------------------------------------------------------------------------
// 3. Per-node attention scores (one wave per node).
// ---------------------------------------------------------------------------
__global__ __launch_bounds__(64) void scores_kernel(
    const float* __restrict__ h, const float* __restrict__ att_s,
    const float* __restrict__ att_d, float* __restrict__ as_,
    float* __restrict__ ad_, int H, int C) {
    const int n = blockIdx.x, lane = threadIdx.x;
    for (int hh = 0; hh < H; hh++) {
        float s = 0.f, d = 0.f;
        for (int c = lane; c < C; c += 64) {
            float v = h[((size_t)n * H + hh) * C + c];
            s += v * att_s[hh * C + c];
            d += v * att_d[hh * C + c];
        }
#pragma unroll
        for (int off = 32; off; off >>= 1) {
            s += __shfl_xor(s, off);
            d += __shfl_xor(d, off);
        }
        if (lane == 0) { as_[n * H + hh] = s; ad_[n * H + hh] = d; }
    }
}

// ---------------------------------------------------------------------------
// 4. Layer-1 sparse attention aggregate. One block (128 thr) per row i.
//    tid = head(8) x lane16(16); each lane owns 4 channels (float4).
//    Gather loop unrolled x4 with independent accumulators for ILP.
// ---------------------------------------------------------------------------
__global__ __launch_bounds__(128) void attn1_kernel(
    const float* __restrict__ h1, const float* __restrict__ asrc,
    const float* __restrict__ adst, const int* __restrict__ nbr,
    const int* __restrict__ cnt, const float* __restrict__ b1,
    float* __restrict__ out1) {
    const int i   = blockIdx.x;
    const int tid = threadIdx.x;
    const int hs  = tid >> 4;     // head 0..7
    const int l16 = tid & 15;
    __shared__ int   s_nbr[STRIDE];
    __shared__ float s_w[8][SWPAD];    // padded rows: heads on distinct banks
    const int n = cnt[i];
    for (int j = tid; j < n; j += 128) s_nbr[j] = nbr[(size_t)i * STRIDE + j];
    __syncthreads();

    const float ad = adst[i * 8 + hs];
    float m = -1e30f;
    for (int j = l16; j < n; j += 16) {
        float s = asrc[s_nbr[j] * 8 + hs] + ad;
        s = (s > 0.f) ? s : 0.2f * s;
        s_w[hs][j] = s;
        m = fmaxf(m, s);
    }
#pragma unroll
    for (int off = 8; off; off >>= 1) m = fmaxf(m, __shfl_xor(m, off));
    float l = 0.f;
    for (int j = l16; j < n; j += 16) {
        float e = __expf(s_w[hs][j] - m);
        s_w[hs][j] = e;
        l += e;
    }
#pragma unroll
    for (int off = 8; off; off >>= 1) l += __shfl_xor(l, off);
    const float inv = 1.0f / l;
    __syncthreads();

    // pass 3: weighted gather, unrolled x4 (4 in-flight float4 loads/thread)
    const int c0 = hs * 64 + l16 * 4;
    float4 a0 = {0,0,0,0}, a1 = {0,0,0,0}, a2 = {0,0,0,0}, a3 = {0,0,0,0};
    int j = 0;
    for (; j + 4 <= n; j += 4) {
        int i0 = s_nbr[j], i1 = s_nbr[j+1], i2 = s_nbr[j+2], i3 = s_nbr[j+3];
        float w0 = s_w[hs][j],   w1 = s_w[hs][j+1];
        float w2 = s_w[hs][j+2], w3 = s_w[hs][j+3];
        float4 v0 = *(const float4*)(h1 + (size_t)i0 * 512 + c0);
        float4 v1 = *(const float4*)(h1 + (size_t)i1 * 512 + c0);
        float4 v2 = *(const float4*)(h1 + (size_t)i2 * 512 + c0);
        float4 v3 = *(const float4*)(h1 + (size_t)i3 * 512 + c0);
        a0.x += w0*v0.x; a0.y += w0*v0.y; a0.z += w0*v0.z; a0.w += w0*v0.w;
        a1.x += w1*v1.x; a1.y += w1*v1.y; a1.z += w1*v1.z; a1.w += w1*v1.w;
        a2.x += w2*v2.x; a2.y += w2*v2.y; a2.z += w2*v2.z; a2.w += w2*v2.w;
        a3.x += w3*v3.x; a3.y += w3*v3.y; a3.z += w3*v3.z; a3.w += w3*v3.w;
    }
    for (; j < n; j++) {
        float w = s_w[hs][j];
        float4 v = *(const float4*)(h1 + (size_t)s_nbr[j] * 512 + c0);
        a0.x += w*v.x; a0.y += w*v.y; a0.z += w*v.z; a0.w += w*v.w;
    }
    float4 acc = make_float4(a0.x + a1.x + a2.x + a3.x,
                             a0.y + a1.y + a2.y + a3.y,
                             a0.z + a1.z + a2.z + a3.z,
                             a0.w + a1.w + a2.w + a3.w);
    float4 bb = *(const float4*)(b1 + c0);
    float o0 = acc.x * inv + bb.x, o1 = acc.y * inv + bb.y;
    float o2 = acc.z * inv + bb.z, o3 = acc.w * inv + bb.w;
    o0 = (o0 > 0.f) ? o0 : 0.01f * o0;
    o1 = (o1 > 0.f) ? o1 : 0.01f * o1;
    o2 = (o2 > 0.f) ? o2 : 0.01f * o2;
    o3 = (o3 > 0.f) ? o3 : 0.01f * o3;
    *(float4*)(out1 + (size_t)i * 512 + c0) = make_float4(o0, o1, o2, o3);
}

// ---------------------------------------------------------------------------
// 5. Layer-2 sparse attention aggregate (1 head, 128 channels).
// ---------------------------------------------------------------------------
__global__ __launch_bounds__(128) void attn2_kernel(
    const float* __restrict__ h2, const float* __restrict__ asrc,
    const float* __restrict__ adst, const int* __restrict__ nbr,
    const int* __restrict__ cnt, const float* __restrict__ b2,
    float* __restrict__ out) {
    const int i   = blockIdx.x;
    const int tid = threadIdx.x;
    __shared__ int   s_nbr[STRIDE];
    __shared__ float s_w[STRIDE];
    __shared__ float red[2], red2[2];
    const int n = cnt[i];
    for (int j = tid; j < n; j += 128) s_nbr[j] = nbr[(size_t)i * STRIDE + j];
    __syncthreads();

    const float ad = adst[i];
    float mloc = -1e30f;
    for (int j = tid; j < n; j += 128) {
        float s = asrc[s_nbr[j]] + ad;
        s = (s > 0.f) ? s : 0.2f * s;
        s_w[j] = s;
        mloc = fmaxf(mloc, s);
    }
#pragma unroll
    for (int off = 32; off; off >>= 1) mloc = fmaxf(mloc, __shfl_xor(mloc, off));
    if ((tid & 63) == 0) red[tid >> 6] = mloc;
    __syncthreads();
    const float m = fmaxf(red[0], red[1]);
    float lloc = 0.f;
    for (int j = tid; j < n; j += 128) {
        float e = __expf(s_w[j] - m);
        s_w[j] = e;
        lloc += e;
    }
#pragma unroll
    for (int off = 32; off; off >>= 1) lloc += __shfl_xor(lloc, off);
    if ((tid & 63) == 0) red2[tid >> 6] = lloc;
    __syncthreads();
    const float inv = 1.0f / (red2[0] + red2[1]);

    float a0 = 0.f, a1 = 0.f, a2 = 0.f, a3 = 0.f;
    int j = 0;
    for (; j + 4 <= n; j += 4) {
        int i0 = s_nbr[j], i1 = s_nbr[j+1], i2 = s_nbr[j+2], i3 = s_nbr[j+3];
        float w0 = s_w[j], w1 = s_w[j+1], w2 = s_w[j+2], w3 = s_w[j+3];
        float v0 = h2[(size_t)i0 * 128 + tid];
        float v1 = h2[(size_t)i1 * 128 + tid];
        float v2 = h2[(size_t)i2 * 128 + tid];
        float v3 = h2[(size_t)i3 * 128 + tid];
        a0 += w0 * v0; a1 += w1 * v1; a2 += w2 * v2; a3 += w3 * v3;
    }
    for (; j < n; j++) a0 += s_w[j] * h2[(size_t)s_nbr[j] * 128 + tid];
    float o = (a0 + a1 + a2 + a3) * inv + b2[tid];
    out[(size_t)i * 128 + tid] = (o > 0.f) ? o : 0.01f * o;
}

// ---------------------------------------------------------------------------
extern "C" void kernel_launch(void* const* d_in, const int* in_sizes, int n_in,
                              void* d_out, int out_size, void* d_ws, size_t ws_size,
                              hipStream_t stream) {
    const float* x        = (const float*)d_in[0];   // [4096,256]
    const float* adj      = (const float*)d_in[1];   // [4096,4096]
    const float* w1       = (const float*)d_in[2];   // [256,512]
    const float* att_src1 = (const float*)d_in[3];   // [8,64]
    const float* att_dst1 = (const float*)d_in[4];
    const float* b1       = (const float*)d_in[5];   // [512]
    const float* w2       = (const float*)d_in[6];   // [512,128]
    const float* att_src2 = (const float*)d_in[7];   // [1,128]
    const float* att_dst2 = (const float*)d_in[8];
    const float* b2       = (const float*)d_in[9];   // [128]
    float* out = (float*)d_out;                      // [4096,128]

    float* ws   = (float*)d_ws;
    float* h1   = ws;                         // 4096*512
    float* out1 = h1 + 4096 * 512;            // 4096*512
    float* h2   = out1 + 4096 * 512;          // 4096*128
    float* as1  = h2 + 4096 * 128;            // 4096*8
    float* ad1  = as1 + 4096 * 8;             // 4096*8
    float* as2  = ad1 + 4096 * 8;             // 4096
    float* ad2  = as2 + 4096;                 // 4096
    int*   cnt  = (int*)(ad2 + 4096);         // 4096
    int*   nbr  = (int*)(cnt + 4096);         // 4096*STRIDE

    build_nbr_kernel<<<N_NODES, 64, 0, stream>>>(adj, nbr, cnt);

    // layer 1: h1 = x @ w1   (4096x256 @ 256x512)
    sgemm_kernel<64, 128, 16, 4, 8><<<dim3(512 / 128, 4096 / 64), 256, 0, stream>>>(
        x, w1, h1, 4096, 512, 256);
    scores_kernel<<<N_NODES, 64, 0, stream>>>(h1, att_src1, att_dst1, as1, ad1, 8, 64);
    attn1_kernel<<<N_NODES, 128, 0, stream>>>(h1, as1, ad1, nbr, cnt, b1, out1);

    // layer 2: h2 = out1 @ w2  (4096x512 @ 512x128)
    sgemm_kernel<32, 128, 16, 2, 8><<<dim3(128 / 128, 4096 / 32), 256, 0, stream>>>(
        out1, w2, h2, 4096, 128, 512);
    scores_kernel<<<N_NODES, 64, 0, stream>>>(h2, att_src2, att_dst2, as2, ad2, 1, 128);
    attn2_kernel<<<N_NODES, 128, 0, stream>>>(h2, as2, ad2, nbr, cnt, b2, out);
}

// Round 3
// 299.796 us; speedup vs baseline: 1.2791x; 1.1027x over previous
//
#include <hip/hip_runtime.h>
#include <hip/hip_bf16.h>
#include <cstdint>

#define N_NODES 4096
#define STRIDE  384      // max degree ~205+12sigma (Binom(4096,0.05))
#define SWPAD   (STRIDE + 8)

// ---------------------------------------------------------------------------
// 1. Neighbor-list compaction: one wave per row, float4 loads + 4 ballots.
// ---------------------------------------------------------------------------
__global__ __launch_bounds__(64) void build_nbr_kernel(
    const float* __restrict__ adj, int* __restrict__ nbr, int* __restrict__ cnt) {
    const int i    = blockIdx.x;
    const int lane = threadIdx.x;
    const float4* row = (const float4*)(adj + (size_t)i * N_NODES);
    int base = 0;
    for (int jb = 0; jb < N_NODES / 4; jb += 64) {   // 16 iterations
        float4 v = row[jb + lane];
        float e4[4] = {v.x, v.y, v.z, v.w};
        unsigned long long m4[4];
#pragma unroll
        for (int e = 0; e < 4; e++) m4[e] = __ballot(e4[e] != 0.0f);
#pragma unroll
        for (int e = 0; e < 4; e++) {
            int prefix = __popcll(m4[e] & ((1ull << lane) - 1ull));
            int pos = base + prefix;
            if (e4[e] != 0.0f && pos < STRIDE)
                nbr[(size_t)i * STRIDE + pos] = (jb + lane) * 4 + e;
            base += __popcll(m4[e]);
        }
    }
    if (lane == 0) cnt[i] = (base < STRIDE) ? base : STRIDE;
}

// ---------------------------------------------------------------------------
// 2. Tiled fp32 GEMM: C[M,N] = A[M,K] @ B[K,N]. 256 threads,
//    (BM/TM)x(BN/TN)=256 thread grid, float4 global loads, A staged K-major.
// ---------------------------------------------------------------------------
template<int BM, int BN, int BK, int TM, int TN>
__global__ __launch_bounds__(256) void sgemm_kernel(
    const float* __restrict__ A, const float* __restrict__ B,
    float* __restrict__ C, int M, int N, int K) {
    static_assert((BM / TM) * (BN / TN) == 256, "256 threads");
    __shared__ float As[BK][BM + 4];
    __shared__ float Bs[BK][BN + 4];
    const int tid  = threadIdx.x;
    const int tx   = tid % (BN / TN);
    const int ty   = tid / (BN / TN);
    const int row0 = blockIdx.y * BM;
    const int col0 = blockIdx.x * BN;
    float acc[TM][TN] = {};
    for (int k0 = 0; k0 < K; k0 += BK) {
        for (int i = tid; i < BM * BK / 4; i += 256) {
            int r  = i / (BK / 4);
            int kq = i % (BK / 4);
            float4 v = *(const float4*)(A + (size_t)(row0 + r) * K + k0 + kq * 4);
            As[kq * 4 + 0][r] = v.x;
            As[kq * 4 + 1][r] = v.y;
            As[kq * 4 + 2][r] = v.z;
            As[kq * 4 + 3][r] = v.w;
        }
        for (int i = tid; i < BK * BN / 4; i += 256) {
            int r  = i / (BN / 4);
            int cq = i % (BN / 4);
            *(float4*)&Bs[r][cq * 4] =
                *(const float4*)(B + (size_t)(k0 + r) * N + col0 + cq * 4);
        }
        __syncthreads();
#pragma unroll
        for (int kk = 0; kk < BK; kk++) {
            float a[TM], b[TN];
#pragma unroll
            for (int t = 0; t < TM; t++) a[t] = As[kk][ty * TM + t];
#pragma unroll
            for (int u = 0; u < TN; u++) b[u] = Bs[kk][tx * TN + u];
#pragma unroll
            for (int t = 0; t < TM; t++)
#pragma unroll
                for (int u = 0; u < TN; u++) acc[t][u] += a[t] * b[u];
        }
        __syncthreads();
    }
#pragma unroll
    for (int t = 0; t < TM; t++)
#pragma unroll
        for (int u4 = 0; u4 < TN / 4; u4++) {
            float4 v = make_float4(acc[t][u4 * 4 + 0], acc[t][u4 * 4 + 1],
                                   acc[t][u4 * 4 + 2], acc[t][u4 * 4 + 3]);
            *(float4*)(C + (size_t)(row0 + ty * TM + t) * N + col0 + tx * TN + u4 * 4) = v;
        }
}

// ---------------------------------------------------------------------------
// 3. Per-node attention scores (one wave per node).
// ---------------------------------------------------------------------------
__global__ __launch_bounds__(64) void scores_kernel(
    const float* __restrict__ h, const float* __restrict__ att_s,
    const float* __restrict__ att_d, float* __restrict__ as_,
    float* __restrict__ ad_, int H, int C) {
    const int n = blockIdx.x, lane = threadIdx.x;
    for (int hh = 0; hh < H; hh++) {
        float s = 0.f, d = 0.f;
        for (int c = lane; c < C; c += 64) {
            float v = h[((size_t)n * H + hh) * C + c];
            s += v * att_s[hh * C + c];
            d += v * att_d[hh * C + c];
        }
#pragma unroll
        for (int off = 32; off; off >>= 1) {
            s += __shfl_xor(s, off);
            d += __shfl_xor(d, off);
        }
        if (lane == 0) { as_[n * H + hh] = s; ad_[n * H + hh] = d; }
    }
}

// ---------------------------------------------------------------------------
// 4. Layer-1 sparse attention aggregate. One block (128 thr) per row i.
//    Pass 1: one thread per EDGE loads a_src[j,0..7] as 2x float4 (32B
//    contiguous) and writes all 8 head scores -> kills the 8x scattered
//    4B gathers. Pass 3: tid = head(8) x lane16(16), float4 gather x4 ILP.
// ---------------------------------------------------------------------------
__global__ __launch_bounds__(128) void attn1_kernel(
    const float* __restrict__ h1, const float* __restrict__ asrc,
    const float* __restrict__ adst, const int* __restrict__ nbr,
    const int* __restrict__ cnt, const float* __restrict__ b1,
    float* __restrict__ out1) {
    const int i   = blockIdx.x;
    const int tid = threadIdx.x;
    const int hs  = tid >> 4;     // head 0..7
    const int l16 = tid & 15;
    __shared__ int   s_nbr[STRIDE];
    __shared__ float s_w[8][SWPAD];
    const int n = cnt[i];
    for (int j = tid; j < n; j += 128) s_nbr[j] = nbr[(size_t)i * STRIDE + j];
    __syncthreads();

    // pass 1: per-edge, all 8 heads per thread (contiguous 32B a_src row)
    const float4 ad0 = *(const float4*)(adst + i * 8);
    const float4 ad1 = *(const float4*)(adst + i * 8 + 4);
    for (int j = tid; j < n; j += 128) {
        const int nj = s_nbr[j];
        float4 p = *(const float4*)(asrc + nj * 8);
        float4 q = *(const float4*)(asrc + nj * 8 + 4);
        float s0 = p.x + ad0.x, s1 = p.y + ad0.y, s2 = p.z + ad0.z, s3 = p.w + ad0.w;
        float s4 = q.x + ad1.x, s5 = q.y + ad1.y, s6 = q.z + ad1.z, s7 = q.w + ad1.w;
        s_w[0][j] = (s0 > 0.f) ? s0 : 0.2f * s0;
        s_w[1][j] = (s1 > 0.f) ? s1 : 0.2f * s1;
        s_w[2][j] = (s2 > 0.f) ? s2 : 0.2f * s2;
        s_w[3][j] = (s3 > 0.f) ? s3 : 0.2f * s3;
        s_w[4][j] = (s4 > 0.f) ? s4 : 0.2f * s4;
        s_w[5][j] = (s5 > 0.f) ? s5 : 0.2f * s5;
        s_w[6][j] = (s6 > 0.f) ? s6 : 0.2f * s6;
        s_w[7][j] = (s7 > 0.f) ? s7 : 0.2f * s7;
    }
    __syncthreads();

    // per-head max (16-lane group scans its head row)
    float m = -1e30f;
    for (int j = l16; j < n; j += 16) m = fmaxf(m, s_w[hs][j]);
#pragma unroll
    for (int off = 8; off; off >>= 1) m = fmaxf(m, __shfl_xor(m, off));
    // exp + sum (same-wave rewrite; no barrier needed before pass 3)
    float l = 0.f;
    for (int j = l16; j < n; j += 16) {
        float e = __expf(s_w[hs][j] - m);
        s_w[hs][j] = e;
        l += e;
    }
#pragma unroll
    for (int off = 8; off; off >>= 1) l += __shfl_xor(l, off);
    const float inv = 1.0f / l;

    // pass 3: weighted gather, x4 ILP
    const int c0 = hs * 64 + l16 * 4;
    float4 a0 = {0,0,0,0}, a1 = {0,0,0,0}, a2 = {0,0,0,0}, a3 = {0,0,0,0};
    int j = 0;
    for (; j + 4 <= n; j += 4) {
        int i0 = s_nbr[j], i1 = s_nbr[j+1], i2 = s_nbr[j+2], i3 = s_nbr[j+3];
        float w0 = s_w[hs][j],   w1 = s_w[hs][j+1];
        float w2 = s_w[hs][j+2], w3 = s_w[hs][j+3];
        float4 v0 = *(const float4*)(h1 + (size_t)i0 * 512 + c0);
        float4 v1 = *(const float4*)(h1 + (size_t)i1 * 512 + c0);
        float4 v2 = *(const float4*)(h1 + (size_t)i2 * 512 + c0);
        float4 v3 = *(const float4*)(h1 + (size_t)i3 * 512 + c0);
        a0.x += w0*v0.x; a0.y += w0*v0.y; a0.z += w0*v0.z; a0.w += w0*v0.w;
        a1.x += w1*v1.x; a1.y += w1*v1.y; a1.z += w1*v1.z; a1.w += w1*v1.w;
        a2.x += w2*v2.x; a2.y += w2*v2.y; a2.z += w2*v2.z; a2.w += w2*v2.w;
        a3.x += w3*v3.x; a3.y += w3*v3.y; a3.z += w3*v3.z; a3.w += w3*v3.w;
    }
    for (; j < n; j++) {
        float w = s_w[hs][j];
        float4 v = *(const float4*)(h1 + (size_t)s_nbr[j] * 512 + c0);
        a0.x += w*v.x; a0.y += w*v.y; a0.z += w*v.z; a0.w += w*v.w;
    }
    float4 acc = make_float4(a0.x + a1.x + a2.x + a3.x,
                             a0.y + a1.y + a2.y + a3.y,
                             a0.z + a1.z + a2.z + a3.z,
                             a0.w + a1.w + a2.w + a3.w);
    float4 bb = *(const float4*)(b1 + c0);
    float o0 = acc.x * inv + bb.x, o1 = acc.y * inv + bb.y;
    float o2 = acc.z * inv + bb.z, o3 = acc.w * inv + bb.w;
    o0 = (o0 > 0.f) ? o0 : 0.01f * o0;
    o1 = (o1 > 0.f) ? o1 : 0.01f * o1;
    o2 = (o2 > 0.f) ? o2 : 0.01f * o2;
    o3 = (o3 > 0.f) ? o3 : 0.01f * o3;
    *(float4*)(out1 + (size_t)i * 512 + c0) = make_float4(o0, o1, o2, o3);
}

// ---------------------------------------------------------------------------
// 5. Layer-2 sparse attention aggregate (1 head, 128 channels).
// ---------------------------------------------------------------------------
__global__ __launch_bounds__(128) void attn2_kernel(
    const float* __restrict__ h2, const float* __restrict__ asrc,
    const float* __restrict__ adst, const int* __restrict__ nbr,
    const int* __restrict__ cnt, const float* __restrict__ b2,
    float* __restrict__ out) {
    const int i   = blockIdx.x;
    const int tid = threadIdx.x;
    __shared__ int   s_nbr[STRIDE];
    __shared__ float s_w[STRIDE];
    __shared__ float red[2], red2[2];
    const int n = cnt[i];
    for (int j = tid; j < n; j += 128) s_nbr[j] = nbr[(size_t)i * STRIDE + j];
    __syncthreads();

    const float ad = adst[i];
    float mloc = -1e30f;
    for (int j = tid; j < n; j += 128) {
        float s = asrc[s_nbr[j]] + ad;
        s = (s > 0.f) ? s : 0.2f * s;
        s_w[j] = s;
        mloc = fmaxf(mloc, s);
    }
#pragma unroll
    for (int off = 32; off; off >>= 1) mloc = fmaxf(mloc, __shfl_xor(mloc, off));
    if ((tid & 63) == 0) red[tid >> 6] = mloc;
    __syncthreads();
    const float m = fmaxf(red[0], red[1]);
    float lloc = 0.f;
    for (int j = tid; j < n; j += 128) {
        float e = __expf(s_w[j] - m);
        s_w[j] = e;
        lloc += e;
    }
#pragma unroll
    for (int off = 32; off; off >>= 1) lloc += __shfl_xor(lloc, off);
    if ((tid & 63) == 0) red2[tid >> 6] = lloc;
    __syncthreads();
    const float inv = 1.0f / (red2[0] + red2[1]);

    float a0 = 0.f, a1 = 0.f, a2 = 0.f, a3 = 0.f;
    int j = 0;
    for (; j + 4 <= n; j += 4) {
        int i0 = s_nbr[j], i1 = s_nbr[j+1], i2 = s_nbr[j+2], i3 = s_nbr[j+3];
        float w0 = s_w[j], w1 = s_w[j+1], w2 = s_w[j+2], w3 = s_w[j+3];
        float v0 = h2[(size_t)i0 * 128 + tid];
        float v1 = h2[(size_t)i1 * 128 + tid];
        float v2 = h2[(size_t)i2 * 128 + tid];
        float v3 = h2[(size_t)i3 * 128 + tid];
        a0 += w0 * v0; a1 += w1 * v1; a2 += w2 * v2; a3 += w3 * v3;
    }
    for (; j < n; j++) a0 += s_w[j] * h2[(size_t)s_nbr[j] * 128 + tid];
    float o = (a0 + a1 + a2 + a3) * inv + b2[tid];
    out[(size_t)i * 128 + tid] = (o > 0.f) ? o : 0.01f * o;
}

// ---------------------------------------------------------------------------
extern "C" void kernel_launch(void* const* d_in, const int* in_sizes, int n_in,
                              void* d_out, int out_size, void* d_ws, size_t ws_size,
                              hipStream_t stream) {
    const float* x        = (const float*)d_in[0];   // [4096,256]
    const float* adj      = (const float*)d_in[1];   // [4096,4096]
    const float* w1       = (const float*)d_in[2];   // [256,512]
    const float* att_src1 = (const float*)d_in[3];   // [8,64]
    const float* att_dst1 = (const float*)d_in[4];
    const float* b1       = (const float*)d_in[5];   // [512]
    const float* w2       = (const float*)d_in[6];   // [512,128]
    const float* att_src2 = (const float*)d_in[7];   // [1,128]
    const float* att_dst2 = (const float*)d_in[8];
    const float* b2       = (const float*)d_in[9];   // [128]
    float* out = (float*)d_out;                      // [4096,128]

    float* ws   = (float*)d_ws;
    float* h1   = ws;                         // 4096*512
    float* out1 = h1 + 4096 * 512;            // 4096*512
    float* h2   = out1 + 4096 * 512;          // 4096*128
    float* as1  = h2 + 4096 * 128;            // 4096*8
    float* ad1  = as1 + 4096 * 8;             // 4096*8
    float* as2  = ad1 + 4096 * 8;             // 4096
    float* ad2  = as2 + 4096;                 // 4096
    int*   cnt  = (int*)(ad2 + 4096);         // 4096
    int*   nbr  = (int*)(cnt + 4096);         // 4096*STRIDE

    build_nbr_kernel<<<N_NODES, 64, 0, stream>>>(adj, nbr, cnt);

    // layer 1: h1 = x @ w1   (4096x256 @ 256x512) -- 512 blocks, 8 waves/CU
    sgemm_kernel<64, 64, 16, 4, 4><<<dim3(512 / 64, 4096 / 64), 256, 0, stream>>>(
        x, w1, h1, 4096, 512, 256);
    scores_kernel<<<N_NODES, 64, 0, stream>>>(h1, att_src1, att_dst1, as1, ad1, 8, 64);
    attn1_kernel<<<N_NODES, 128, 0, stream>>>(h1, as1, ad1, nbr, cnt, b1, out1);

    // layer 2: h2 = out1 @ w2  (4096x512 @ 512x128) -- 256 blocks (no idle CUs)
    sgemm_kernel<32, 64, 16, 2, 4><<<dim3(128 / 64, 4096 / 32), 256, 0, stream>>>(
        out1, w2, h2, 4096, 128, 512);
    scores_kernel<<<N_NODES, 64, 0, stream>>>(h2, att_src2, att_dst2, as2, ad2, 1, 128);
    attn2_kernel<<<N_NODES, 128, 0, stream>>>(h2, as2, ad2, nbr, cnt, b2, out);
}

// Round 4
// 260.608 us; speedup vs baseline: 1.4715x; 1.1504x over previous
//
#include <hip/hip_runtime.h>
#include <hip/hip_bf16.h>
#include <cstdint>

#define N_NODES 4096
#define STRIDE  384      // max degree ~261 expected (Binom(4096,0.05) max-order stat)
#define SWPAD   (STRIDE + 8)

// bf16 helpers (manual, RNE encode / shift decode — no header surprises)
__device__ __forceinline__ unsigned short f2bf(float f) {
    unsigned u = __float_as_uint(f);
    unsigned r = u + 0x7fffu + ((u >> 16) & 1u);
    return (unsigned short)(r >> 16);
}
__device__ __forceinline__ float bf2f(unsigned short h) {
    return __uint_as_float((unsigned)h << 16);
}

// ---------------------------------------------------------------------------
// 1. Neighbor-list compaction: one wave per row, float4 loads + 4 ballots.
//    Node ids < 4096 -> uint16 storage (halves nbr traffic, 3 MB table).
// ---------------------------------------------------------------------------
__global__ __launch_bounds__(64) void build_nbr_kernel(
    const float* __restrict__ adj, unsigned short* __restrict__ nbr,
    int* __restrict__ cnt) {
    const int i    = blockIdx.x;
    const int lane = threadIdx.x;
    const float4* row = (const float4*)(adj + (size_t)i * N_NODES);
    int base = 0;
    for (int jb = 0; jb < N_NODES / 4; jb += 64) {   // 16 iterations
        float4 v = row[jb + lane];
        float e4[4] = {v.x, v.y, v.z, v.w};
        unsigned long long m4[4];
#pragma unroll
        for (int e = 0; e < 4; e++) m4[e] = __ballot(e4[e] != 0.0f);
#pragma unroll
        for (int e = 0; e < 4; e++) {
            int prefix = __popcll(m4[e] & ((1ull << lane) - 1ull));
            int pos = base + prefix;
            if (e4[e] != 0.0f && pos < STRIDE)
                nbr[(size_t)i * STRIDE + pos] = (unsigned short)((jb + lane) * 4 + e);
            base += __popcll(m4[e]);
        }
    }
    if (lane == 0) cnt[i] = (base < STRIDE) ? base : STRIDE;
}

// ---------------------------------------------------------------------------
// 2. Tiled fp32 GEMM (BK=32: half the barriers of BK=16).
// ---------------------------------------------------------------------------
template<int BM, int BN, int BK, int TM, int TN>
__global__ __launch_bounds__(256) void sgemm_kernel(
    const float* __restrict__ A, const float* __restrict__ B,
    float* __restrict__ C, int M, int N, int K) {
    static_assert((BM / TM) * (BN / TN) == 256, "256 threads");
    __shared__ float As[BK][BM + 4];
    __shared__ float Bs[BK][BN + 4];
    const int tid  = threadIdx.x;
    const int tx   = tid % (BN / TN);
    const int ty   = tid / (BN / TN);
    const int row0 = blockIdx.y * BM;
    const int col0 = blockIdx.x * BN;
    float acc[TM][TN] = {};
    for (int k0 = 0; k0 < K; k0 += BK) {
        for (int i = tid; i < BM * BK / 4; i += 256) {
            int r  = i / (BK / 4);
            int kq = i % (BK / 4);
            float4 v = *(const float4*)(A + (size_t)(row0 + r) * K + k0 + kq * 4);
            As[kq * 4 + 0][r] = v.x;
            As[kq * 4 + 1][r] = v.y;
            As[kq * 4 + 2][r] = v.z;
            As[kq * 4 + 3][r] = v.w;
        }
        for (int i = tid; i < BK * BN / 4; i += 256) {
            int r  = i / (BN / 4);
            int cq = i % (BN / 4);
            *(float4*)&Bs[r][cq * 4] =
                *(const float4*)(B + (size_t)(k0 + r) * N + col0 + cq * 4);
        }
        __syncthreads();
#pragma unroll
        for (int kk = 0; kk < BK; kk++) {
            float a[TM], b[TN];
#pragma unroll
            for (int t = 0; t < TM; t++) a[t] = As[kk][ty * TM + t];
#pragma unroll
            for (int u = 0; u < TN; u++) b[u] = Bs[kk][tx * TN + u];
#pragma unroll
            for (int t = 0; t < TM; t++)
#pragma unroll
                for (int u = 0; u < TN; u++) acc[t][u] += a[t] * b[u];
        }
        __syncthreads();
    }
#pragma unroll
    for (int t = 0; t < TM; t++)
#pragma unroll
        for (int u4 = 0; u4 < TN / 4; u4++) {
            float4 v = make_float4(acc[t][u4 * 4 + 0], acc[t][u4 * 4 + 1],
                                   acc[t][u4 * 4 + 2], acc[t][u4 * 4 + 3]);
            *(float4*)(C + (size_t)(row0 + ty * TM + t) * N + col0 + tx * TN + u4 * 4) = v;
        }
}

// ---------------------------------------------------------------------------
// 3a. Layer-1 scores + bf16 shadow copy of h1 (one wave per node).
//     Lane owns 8 channels (2x float4); head hh = lanes hh*8..hh*8+7.
// ---------------------------------------------------------------------------
__global__ __launch_bounds__(64) void scores1_kernel(
    const float* __restrict__ h, const float* __restrict__ att_s,
    const float* __restrict__ att_d, float* __restrict__ as_,
    float* __restrict__ ad_, unsigned short* __restrict__ hg) {
    const int n = blockIdx.x, lane = threadIdx.x;
    const float4 a  = *(const float4*)(h + (size_t)n * 512 + lane * 8);
    const float4 b  = *(const float4*)(h + (size_t)n * 512 + lane * 8 + 4);
    const float4 sa = *(const float4*)(att_s + lane * 8);
    const float4 sb = *(const float4*)(att_s + lane * 8 + 4);
    const float4 da = *(const float4*)(att_d + lane * 8);
    const float4 db = *(const float4*)(att_d + lane * 8 + 4);
    float s = a.x*sa.x + a.y*sa.y + a.z*sa.z + a.w*sa.w
            + b.x*sb.x + b.y*sb.y + b.z*sb.z + b.w*sb.w;
    float d = a.x*da.x + a.y*da.y + a.z*da.z + a.w*da.w
            + b.x*db.x + b.y*db.y + b.z*db.z + b.w*db.w;
#pragma unroll
    for (int off = 1; off < 8; off <<= 1) {
        s += __shfl_xor(s, off);
        d += __shfl_xor(d, off);
    }
    if ((lane & 7) == 0) {
        as_[n * 8 + (lane >> 3)] = s;
        ad_[n * 8 + (lane >> 3)] = d;
    }
    // bf16 copy: pack 8 values -> uint4 (16 B) store
    uint4 p;
    p.x = (unsigned)f2bf(a.x) | ((unsigned)f2bf(a.y) << 16);
    p.y = (unsigned)f2bf(a.z) | ((unsigned)f2bf(a.w) << 16);
    p.z = (unsigned)f2bf(b.x) | ((unsigned)f2bf(b.y) << 16);
    p.w = (unsigned)f2bf(b.z) | ((unsigned)f2bf(b.w) << 16);
    *(uint4*)(hg + (size_t)n * 512 + lane * 8) = p;
}

// ---------------------------------------------------------------------------
// 3b. Layer-2 scores + bf16 shadow copy of h2 (one wave per node, C=128,H=1).
// ---------------------------------------------------------------------------
__global__ __launch_bounds__(64) void scores2_kernel(
    const float* __restrict__ h, const float* __restrict__ att_s,
    const float* __restrict__ att_d, float* __restrict__ as_,
    float* __restrict__ ad_, unsigned short* __restrict__ hg) {
    const int n = blockIdx.x, lane = threadIdx.x;
    float v0 = h[(size_t)n * 128 + lane];
    float v1 = h[(size_t)n * 128 + lane + 64];
    float s = v0 * att_s[lane] + v1 * att_s[lane + 64];
    float d = v0 * att_d[lane] + v1 * att_d[lane + 64];
#pragma unroll
    for (int off = 32; off; off >>= 1) {
        s += __shfl_xor(s, off);
        d += __shfl_xor(d, off);
    }
    if (lane == 0) { as_[n] = s; ad_[n] = d; }
    hg[(size_t)n * 128 + lane]      = f2bf(v0);
    hg[(size_t)n * 128 + lane + 64] = f2bf(v1);
}

// ---------------------------------------------------------------------------
// 4. Layer-1 sparse attention aggregate. One block (128 thr) per row i.
//    Pass 1: per-head 4B score gathers (R2 style -- measured faster than the
//    per-edge float4 variant). Pass 3: bf16 gather (ushort4 = 8 B/lane).
// ---------------------------------------------------------------------------
__global__ __launch_bounds__(128) void attn1_kernel(
    const unsigned short* __restrict__ h1g, const float* __restrict__ asrc,
    const float* __restrict__ adst, const unsigned short* __restrict__ nbr,
    const int* __restrict__ cnt, const float* __restrict__ b1,
    float* __restrict__ out1) {
    const int i   = blockIdx.x;
    const int tid = threadIdx.x;
    const int hs  = tid >> 4;     // head 0..7
    const int l16 = tid & 15;
    __shared__ unsigned short s_nbr[STRIDE];
    __shared__ float s_w[8][SWPAD];
    const int n = cnt[i];
    for (int j = tid; j < n; j += 128) s_nbr[j] = nbr[(size_t)i * STRIDE + j];
    __syncthreads();

    const float ad = adst[i * 8 + hs];
    float m = -1e30f;
    for (int j = l16; j < n; j += 16) {
        float s = asrc[(int)s_nbr[j] * 8 + hs] + ad;
        s = (s > 0.f) ? s : 0.2f * s;
        s_w[hs][j] = s;
        m = fmaxf(m, s);
    }
#pragma unroll
    for (int off = 8; off; off >>= 1) m = fmaxf(m, __shfl_xor(m, off));
    float l = 0.f;
    for (int j = l16; j < n; j += 16) {
        float e = __expf(s_w[hs][j] - m);
        s_w[hs][j] = e;
        l += e;
    }
#pragma unroll
    for (int off = 8; off; off >>= 1) l += __shfl_xor(l, off);
    const float inv = 1.0f / l;
    // s_w written & read by same 16-lane group within wave: no barrier needed

    // pass 3: bf16 weighted gather, x4 ILP (8 B/lane, 512 B/wave per j)
    const int c0 = hs * 64 + l16 * 4;
    float4 a0 = {0,0,0,0}, a1 = {0,0,0,0}, a2 = {0,0,0,0}, a3 = {0,0,0,0};
    int j = 0;
    for (; j + 4 <= n; j += 4) {
        int i0 = s_nbr[j], i1 = s_nbr[j+1], i2 = s_nbr[j+2], i3 = s_nbr[j+3];
        float w0 = s_w[hs][j],   w1 = s_w[hs][j+1];
        float w2 = s_w[hs][j+2], w3 = s_w[hs][j+3];
        ushort4 v0 = *(const ushort4*)(h1g + (size_t)i0 * 512 + c0);
        ushort4 v1 = *(const ushort4*)(h1g + (size_t)i1 * 512 + c0);
        ushort4 v2 = *(const ushort4*)(h1g + (size_t)i2 * 512 + c0);
        ushort4 v3 = *(const ushort4*)(h1g + (size_t)i3 * 512 + c0);
        a0.x += w0*bf2f(v0.x); a0.y += w0*bf2f(v0.y); a0.z += w0*bf2f(v0.z); a0.w += w0*bf2f(v0.w);
        a1.x += w1*bf2f(v1.x); a1.y += w1*bf2f(v1.y); a1.z += w1*bf2f(v1.z); a1.w += w1*bf2f(v1.w);
        a2.x += w2*bf2f(v2.x); a2.y += w2*bf2f(v2.y); a2.z += w2*bf2f(v2.z); a2.w += w2*bf2f(v2.w);
        a3.x += w3*bf2f(v3.x); a3.y += w3*bf2f(v3.y); a3.z += w3*bf2f(v3.z); a3.w += w3*bf2f(v3.w);
    }
    for (; j < n; j++) {
        float w = s_w[hs][j];
        ushort4 v = *(const ushort4*)(h1g + (size_t)s_nbr[j] * 512 + c0);
        a0.x += w*bf2f(v.x); a0.y += w*bf2f(v.y); a0.z += w*bf2f(v.z); a0.w += w*bf2f(v.w);
    }
    float4 acc = make_float4(a0.x + a1.x + a2.x + a3.x,
                             a0.y + a1.y + a2.y + a3.y,
                             a0.z + a1.z + a2.z + a3.z,
                             a0.w + a1.w + a2.w + a3.w);
    float4 bb = *(const float4*)(b1 + c0);
    float o0 = acc.x * inv + bb.x, o1 = acc.y * inv + bb.y;
    float o2 = acc.z * inv + bb.z, o3 = acc.w * inv + bb.w;
    o0 = (o0 > 0.f) ? o0 : 0.01f * o0;
    o1 = (o1 > 0.f) ? o1 : 0.01f * o1;
    o2 = (o2 > 0.f) ? o2 : 0.01f * o2;
    o3 = (o3 > 0.f) ? o3 : 0.01f * o3;
    *(float4*)(out1 + (size_t)i * 512 + c0) = make_float4(o0, o1, o2, o3);
}

// ---------------------------------------------------------------------------
// 5. Layer-2 sparse attention aggregate (1 head, 128 ch), bf16 gather.
// ---------------------------------------------------------------------------
__global__ __launch_bounds__(128) void attn2_kernel(
    const unsigned short* __restrict__ h2g, const float* __restrict__ asrc,
    const float* __restrict__ adst, const unsigned short* __restrict__ nbr,
    const int* __restrict__ cnt, const float* __restrict__ b2,
    float* __restrict__ out) {
    const int i   = blockIdx.x;
    const int tid = threadIdx.x;
    __shared__ unsigned short s_nbr[STRIDE];
    __shared__ float s_w[STRIDE];
    __shared__ float red[2], red2[2];
    const int n = cnt[i];
    for (int j = tid; j < n; j += 128) s_nbr[j] = nbr[(size_t)i * STRIDE + j];
    __syncthreads();

    const float ad = adst[i];
    float mloc = -1e30f;
    for (int j = tid; j < n; j += 128) {
        float s = asrc[(int)s_nbr[j]] + ad;
        s = (s > 0.f) ? s : 0.2f * s;
        s_w[j] = s;
        mloc = fmaxf(mloc, s);
    }
#pragma unroll
    for (int off = 32; off; off >>= 1) mloc = fmaxf(mloc, __shfl_xor(mloc, off));
    if ((tid & 63) == 0) red[tid >> 6] = mloc;
    __syncthreads();
    const float m = fmaxf(red[0], red[1]);
    float lloc = 0.f;
    for (int j = tid; j < n; j += 128) {
        float e = __expf(s_w[j] - m);
        s_w[j] = e;
        lloc += e;
    }
#pragma unroll
    for (int off = 32; off; off >>= 1) lloc += __shfl_xor(lloc, off);
    if ((tid & 63) == 0) red2[tid >> 6] = lloc;
    __syncthreads();
    const float inv = 1.0f / (red2[0] + red2[1]);

    float a0 = 0.f, a1 = 0.f, a2 = 0.f, a3 = 0.f;
    int j = 0;
    for (; j + 4 <= n; j += 4) {
        int i0 = s_nbr[j], i1 = s_nbr[j+1], i2 = s_nbr[j+2], i3 = s_nbr[j+3];
        float w0 = s_w[j], w1 = s_w[j+1], w2 = s_w[j+2], w3 = s_w[j+3];
        float v0 = bf2f(h2g[(size_t)i0 * 128 + tid]);
        float v1 = bf2f(h2g[(size_t)i1 * 128 + tid]);
        float v2 = bf2f(h2g[(size_t)i2 * 128 + tid]);
        float v3 = bf2f(h2g[(size_t)i3 * 128 + tid]);
        a0 += w0 * v0; a1 += w1 * v1; a2 += w2 * v2; a3 += w3 * v3;
    }
    for (; j < n; j++) a0 += s_w[j] * bf2f(h2g[(size_t)s_nbr[j] * 128 + tid]);
    float o = (a0 + a1 + a2 + a3) * inv + b2[tid];
    out[(size_t)i * 128 + tid] = (o > 0.f) ? o : 0.01f * o;
}

// ---------------------------------------------------------------------------
extern "C" void kernel_launch(void* const* d_in, const int* in_sizes, int n_in,
                              void* d_out, int out_size, void* d_ws, size_t ws_size,
                              hipStream_t stream) {
    const float* x        = (const float*)d_in[0];   // [4096,256]
    const float* adj      = (const float*)d_in[1];   // [4096,4096]
    const float* w1       = (const float*)d_in[2];   // [256,512]
    const float* att_src1 = (const float*)d_in[3];   // [8,64]
    const float* att_dst1 = (const float*)d_in[4];
    const float* b1       = (const float*)d_in[5];   // [512]
    const float* w2       = (const float*)d_in[6];   // [512,128]
    const float* att_src2 = (const float*)d_in[7];   // [1,128]
    const float* att_dst2 = (const float*)d_in[8];
    const float* b2       = (const float*)d_in[9];   // [128]
    float* out = (float*)d_out;                      // [4096,128]

    float* ws   = (float*)d_ws;
    float* h1   = ws;                               // 4096*512 f
    float* out1 = h1 + 4096 * 512;                  // 4096*512 f
    float* h2   = out1 + 4096 * 512;                // 4096*128 f
    float* as1  = h2 + 4096 * 128;                  // 4096*8 f
    float* ad1  = as1 + 4096 * 8;                   // 4096*8 f
    float* as2  = ad1 + 4096 * 8;                   // 4096 f
    float* ad2  = as2 + 4096;                       // 4096 f
    int*   cnt  = (int*)(ad2 + 4096);               // 4096 i32
    unsigned short* nbr = (unsigned short*)(cnt + 4096);   // 4096*STRIDE u16
    unsigned short* h1g = nbr + (size_t)4096 * STRIDE;     // 4096*512 u16 (4 MB)
    unsigned short* h2g = h1g + (size_t)4096 * 512;        // 4096*128 u16 (1 MB)

    build_nbr_kernel<<<N_NODES, 64, 0, stream>>>(adj, nbr, cnt);

    // layer 1: h1 = x @ w1   (4096x256 @ 256x512) -- 512 blocks
    sgemm_kernel<64, 64, 32, 4, 4><<<dim3(512 / 64, 4096 / 64), 256, 0, stream>>>(
        x, w1, h1, 4096, 512, 256);
    scores1_kernel<<<N_NODES, 64, 0, stream>>>(h1, att_src1, att_dst1, as1, ad1, h1g);
    attn1_kernel<<<N_NODES, 128, 0, stream>>>(h1g, as1, ad1, nbr, cnt, b1, out1);

    // layer 2: h2 = out1 @ w2  (4096x512 @ 512x128) -- 256 blocks
    sgemm_kernel<32, 64, 32, 2, 4><<<dim3(128 / 64, 4096 / 32), 256, 0, stream>>>(
        out1, w2, h2, 4096, 128, 512);
    scores2_kernel<<<N_NODES, 64, 0, stream>>>(h2, att_src2, att_dst2, as2, ad2, h2g);
    attn2_kernel<<<N_NODES, 128, 0, stream>>>(h2g, as2, ad2, nbr, cnt, b2, out);
}